// Round 13
// baseline (432.699 us; speedup 1.0000x reference)
//
#include <hip/hip_runtime.h>
#include <hip/hip_cooperative_groups.h>
#include <hip/hip_bf16.h>
#include <cstdint>
#include <cstddef>

namespace cg = cooperative_groups;

#define VOCAB  50000
#define EMBED  256
#define HIDDEN 512
#define BATCH  64
#define SEQ    200
#define H2     1024
#define XDIM   1280   // EMBED + H2
#define G3     1536   // 3*HIDDEN
#define V4     (VOCAB/4)
#define NVB    782           // 64-col vocab tiles (782*64 >= 50000)
#define NVBP   784           // Spart row stride
#define NFB    13            // finalize chunks per row (13*4096 >= 50000)
#define NHS    2             // scc H-slices per row
#define GRID   512           // well under R6's proven 846-block coop capacity
#define GEMMB  384           // P3 vocab GEMM blocks (grid-stride over NVB tiles)
#define FINB   448           // P4 finalize blocks (grid-stride over 64*NFB tasks)

typedef __attribute__((ext_vector_type(8))) short short8;
typedef __attribute__((ext_vector_type(4))) float f32x4;

__device__ __forceinline__ short f2bf(float f) {
  uint32_t u = __builtin_bit_cast(uint32_t, f);
  uint32_t r = (u + 0x7fffu + ((u >> 16) & 1u)) >> 16;
  return (short)(r & 0xffffu);
}

__device__ __forceinline__ short8 pack8(float4 v0, float4 v1) {
  short8 fr;
  fr[0]=f2bf(v0.x); fr[1]=f2bf(v0.y); fr[2]=f2bf(v0.z); fr[3]=f2bf(v0.w);
  fr[4]=f2bf(v1.x); fr[5]=f2bf(v1.y); fr[6]=f2bf(v1.z); fr[7]=f2bf(v1.w);
  return fr;
}

// ---------------------------------------------------------------------------
// Single cooperative dispatch, 4 phases, 3 grid.sync()s.
// R12 lesson: 896 blocks + fat dual-tile GEMM failed to launch (capacity);
// here 512 blocks + the R9-proven low-VGPR single-tile GEMM, grid-strided.
// No live register state across grid.sync (R6 spill lesson).
// ---------------------------------------------------------------------------
__launch_bounds__(256, 4)
__global__ void mega(const int* __restrict__ input_idx, const float* __restrict__ encoded,
                     const int* __restrict__ enc_idx, const float* __restrict__ prev_state,
                     const float* __restrict__ weighted, const float* __restrict__ embed,
                     const float* __restrict__ w_ih, const float* __restrict__ w_hh,
                     const float* __restrict__ b_ih, const float* __restrict__ b_hh,
                     const float* __restrict__ wo_w, const float* __restrict__ wo_b,
                     const float* __restrict__ wc_w, const float* __restrict__ wc_b,
                     float* __restrict__ out0, float* __restrict__ out_state,
                     float* __restrict__ out_wnew,
                     float* __restrict__ gxp, float* __restrict__ ghp,
                     unsigned short* __restrict__ stateF, float* __restrict__ stateWS,
                     float* __restrict__ sccp, float* __restrict__ Spart) {
  cg::grid_group grid = cg::this_grid();
  __shared__ __align__(16) short As[4 * 64 * 8];   // 4 KB
  __shared__ float red[256];                        // 1 KB (reduction / attn)
  __shared__ float mp[SEQ];
  __shared__ int   me[SEQ];
  __shared__ int   act[SEQ];
  __shared__ int   cnt;
  __shared__ float fnorm_sh;
  const int bid = blockIdx.x;
  const int tid = threadIdx.x;
  const int wave = tid >> 6, lane = tid & 63;
  const int l15  = lane & 15, lk = lane >> 4;

  // ================= P1: GRU partial GEMMs (288 active blocks) =============
  if (bid < 288) {
    const int bx = bid % 24, slice = bid / 24;
    const bool isX  = slice < 8;
    const float* B  = isX ? w_ih : w_hh;
    const int ldb   = isX ? XDIM : HIDDEN;
    const int kbeg  = isX ? slice * 160 : (slice - 8) * 128;
    const int kend  = kbeg + (isX ? 160 : 128);
    float* C = isX ? (gxp + (size_t)slice * BATCH * G3)
                   : (ghp + (size_t)(slice - 8) * BATCH * G3);
    const int ncol = bx * 64 + wave * 16;

    f32x4 acc0 = {0,0,0,0}, acc1 = {0,0,0,0}, acc2 = {0,0,0,0}, acc3 = {0,0,0,0};
    const int sl  = tid & 63;
    const int sm  = (tid >> 6) * 16 + (sl & 15);
    const int skb = (sl >> 4) * 8;
    const int nrow = ncol + l15;
    const float* Bbase = B + (size_t)nrow * ldb + lk * 8;

    for (int kc = kbeg; kc < kend; kc += 32) {
      {
        const float4* ap;
        if (isX) {
          int col = kc + skb;
          if (col < EMBED) ap = reinterpret_cast<const float4*>(embed + (size_t)input_idx[sm] * EMBED + col);
          else             ap = reinterpret_cast<const float4*>(weighted + (size_t)sm * H2 + (col - EMBED));
        } else {
          ap = reinterpret_cast<const float4*>(prev_state + (size_t)sm * HIDDEN + kc + skb);
        }
        *reinterpret_cast<short8*>(&As[tid * 8]) = pack8(ap[0], ap[1]);
      }
      __syncthreads();
      short8 bf;
      {
        const float4* bp = reinterpret_cast<const float4*>(Bbase + kc);
        bf = pack8(bp[0], bp[1]);
      }
      short8 a0 = *reinterpret_cast<const short8*>(&As[(0*64 + lane)*8]);
      short8 a1 = *reinterpret_cast<const short8*>(&As[(1*64 + lane)*8]);
      short8 a2 = *reinterpret_cast<const short8*>(&As[(2*64 + lane)*8]);
      short8 a3 = *reinterpret_cast<const short8*>(&As[(3*64 + lane)*8]);
      acc0 = __builtin_amdgcn_mfma_f32_16x16x32_bf16(a0, bf, acc0, 0, 0, 0);
      acc1 = __builtin_amdgcn_mfma_f32_16x16x32_bf16(a1, bf, acc1, 0, 0, 0);
      acc2 = __builtin_amdgcn_mfma_f32_16x16x32_bf16(a2, bf, acc2, 0, 0, 0);
      acc3 = __builtin_amdgcn_mfma_f32_16x16x32_bf16(a3, bf, acc3, 0, 0, 0);
      __syncthreads();
    }
    const int n = ncol + l15;
    #pragma unroll
    for (int r = 0; r < 4; ++r) {
      C[(size_t)(0*16 + lk*4 + r) * G3 + n] = acc0[r];
      C[(size_t)(1*16 + lk*4 + r) * G3 + n] = acc1[r];
      C[(size_t)(2*16 + lk*4 + r) * G3 + n] = acc2[r];
      C[(size_t)(3*16 + lk*4 + r) * G3 + n] = acc3[r];
    }
  }
  __threadfence();
  grid.sync();                                       // ---- sync 1

  // ================= P2: GRU gates (128 active blocks) =====================
  if (bid < 128) {
    int i = bid * 256 + tid;
    int b = i >> 9, h = i & 511;
    float xr = b_ih[h], xz = b_ih[HIDDEN + h], xn = b_ih[2*HIDDEN + h];
    #pragma unroll
    for (int s = 0; s < 8; ++s) {
      const float* g = gxp + (size_t)s * BATCH * G3 + (size_t)b * G3;
      xr += g[h]; xz += g[HIDDEN + h]; xn += g[2*HIDDEN + h];
    }
    float hr = b_hh[h], hz = b_hh[HIDDEN + h], hn = b_hh[2*HIDDEN + h];
    #pragma unroll
    for (int s = 0; s < 4; ++s) {
      const float* g = ghp + (size_t)s * BATCH * G3 + (size_t)b * G3;
      hr += g[h]; hz += g[HIDDEN + h]; hn += g[2*HIDDEN + h];
    }
    float r = 1.f / (1.f + __expf(-(xr + hr)));
    float z = 1.f / (1.f + __expf(-(xz + hz)));
    float n = tanhf(xn + r * hn);
    float st = (1.f - z) * n + z * prev_state[(size_t)b*HIDDEN + h];
    out_state[(size_t)b*HIDDEN + h] = st;
    stateWS[(size_t)b*HIDDEN + h] = st;
    int fi = ((h >> 5) * 4 + (b >> 4)) * 512 + ((b & 15) + 16 * ((h >> 3) & 3)) * 8 + (h & 7);
    stateF[fi] = (unsigned short)f2bf(st);
  }
  __threadfence();
  grid.sync();                                       // ---- sync 2

  // ====== P3: scc riders (128 blocks) + vocab GEMM (384 blocks, strided) ===
  if (bid < BATCH * NHS) {
    const int b = bid >> 1, hs = bid & 1;            // 2 slices x 256 h each
    const int in0 = input_idx[b];
    if (tid < SEQ) {
      int e = enc_idx[b*SEQ + tid];
      act[tid] = (e != 0 && e == in0);
      sccp[(size_t)(b*SEQ + tid)*NHS + hs] = 0.f;
    }
    __syncthreads();
    const int h = hs*256 + tid;
    const float4* wr = reinterpret_cast<const float4*>(wc_w + (size_t)h*H2);
    const float  sh  = stateWS[(size_t)b*HIDDEN + h];
    const float  bh  = wc_b[h];
    for (int sq = 0; sq < SEQ; ++sq) {
      if (act[sq]) {
        const float4* er = reinterpret_cast<const float4*>(encoded + (size_t)b*SEQ*H2 + (size_t)sq*H2);
        float d = 0.f;
        #pragma unroll 8
        for (int k = 0; k < H2/4; ++k) {
          float4 a = er[k], w = wr[k];
          d += a.x*w.x + a.y*w.y + a.z*w.z + a.w*w.w;
        }
        red[tid] = tanhf(d + bh) * sh;
        __syncthreads();
        for (int off = 128; off > 0; off >>= 1) {
          if (tid < off) red[tid] += red[tid + off];
          __syncthreads();
        }
        if (tid == 0) sccp[(size_t)(b*SEQ + sq)*NHS + hs] = red[0];
        __syncthreads();
      }
    }
  } else {
    // R9-proven single-tile GEMM, grid-stride over 782 column-tiles
    const short8* Af = reinterpret_cast<const short8*>(stateF);
    for (int t = bid - BATCH * NHS; t < NVB; t += GEMMB) {
      __syncthreads();                               // red[] reuse across tiles
      const int ncol = t * 64 + wave * 16;
      int nrow = ncol + l15; if (nrow > VOCAB - 1) nrow = VOCAB - 1;
      const float* Bb = wo_w + (size_t)nrow * HIDDEN + lk * 8;

      f32x4 acc0 = {0,0,0,0}, acc1 = {0,0,0,0}, acc2 = {0,0,0,0}, acc3 = {0,0,0,0};
      #pragma unroll 4
      for (int c = 0; c < 16; ++c) {
        const float4* bp = reinterpret_cast<const float4*>(Bb + c*32);
        float4 b0 = bp[0], b1 = bp[1];
        short8 a0 = Af[(c*4 + 0)*64 + lane];
        short8 a1 = Af[(c*4 + 1)*64 + lane];
        short8 a2 = Af[(c*4 + 2)*64 + lane];
        short8 a3 = Af[(c*4 + 3)*64 + lane];
        short8 bf = pack8(b0, b1);
        acc0 = __builtin_amdgcn_mfma_f32_16x16x32_bf16(a0, bf, acc0, 0, 0, 0);
        acc1 = __builtin_amdgcn_mfma_f32_16x16x32_bf16(a1, bf, acc1, 0, 0, 0);
        acc2 = __builtin_amdgcn_mfma_f32_16x16x32_bf16(a2, bf, acc2, 0, 0, 0);
        acc3 = __builtin_amdgcn_mfma_f32_16x16x32_bf16(a3, bf, acc3, 0, 0, 0);
      }

      const int n = ncol + l15;
      const bool valid = n < VOCAB;
      const float bv = valid ? wo_b[n] : 0.f;
      f32x4 accs[4] = {acc0, acc1, acc2, acc3};
      #pragma unroll
      for (int a = 0; a < 4; ++a) {
        #pragma unroll
        for (int r = 0; r < 4; ++r) {
          float ev = valid ? __expf(accs[a][r] + bv) : 0.f;
          if (valid) out0[(size_t)(a*16 + lk*4 + r) * VOCAB + n] = ev;
          float v = ev;
          v += __shfl_xor(v, 1); v += __shfl_xor(v, 2);
          v += __shfl_xor(v, 4); v += __shfl_xor(v, 8);
          if (l15 == 0) red[wave*64 + a*16 + lk*4 + r] = v;
        }
      }
      __syncthreads();
      if (tid < 64)
        Spart[(size_t)tid * NVBP + t] =
            red[0*64+tid] + red[1*64+tid] + red[2*64+tid] + red[3*64+tid];
    }
  }
  __threadfence();
  grid.sync();                                       // ---- sync 3

  // ====== P4: weighted_new (64 blocks) + finalize (448 blocks, strided) ====
  if (bid < BATCH) {
    const int b = bid;
    const int in0 = input_idx[b];
    if (tid < SEQ) {
      float sc = sccp[(size_t)(b*SEQ + tid)*NHS] + sccp[(size_t)(b*SEQ + tid)*NHS + 1];
      int e = enc_idx[b*SEQ + tid];
      red[tid] = (e == in0) ? __expf(sc) : 0.f;
    } else {
      red[tid] = 0.f;
    }
    __syncthreads();
    if (tid == 0) {
      float s = 0.f;
      for (int i = 0; i < SEQ; ++i) s += red[i];
      fnorm_sh = (s > 0.f) ? 1.f / s : 1.f;
    }
    __syncthreads();
    const float f = fnorm_sh;
    float a0 = 0, a1 = 0, a2 = 0, a3 = 0;
    const float4* ep = reinterpret_cast<const float4*>(encoded + (size_t)b*SEQ*H2);
    for (int s = 0; s < SEQ; ++s) {
      float a = red[s];
      if (a != 0.f) {
        a *= f;
        float4 v = ep[(size_t)s*(H2/4) + tid];
        a0 += a*v.x; a1 += a*v.y; a2 += a*v.z; a3 += a*v.w;
      }
    }
    float4 o = {a0, a1, a2, a3};
    reinterpret_cast<float4*>(out_wnew + (size_t)b*H2)[tid] = o;
  } else {
    for (int q = bid - BATCH; q < BATCH * NFB; q += FINB) {
      __syncthreads();                               // LDS reuse across tasks
      const int b = q / NFB, c = q % NFB;
      if (tid == 0) cnt = 0;
      float ps = 0.f;
      for (int i = tid; i < NVB; i += 256) ps += Spart[(size_t)b * NVBP + i];
      float ex = 0.f;
      int e = -1;
      if (tid < SEQ) {
        float sc = sccp[(size_t)(b*SEQ + tid)*NHS] + sccp[(size_t)(b*SEQ + tid)*NHS + 1];
        ex = __expf(sc);
        e = enc_idx[b*SEQ + tid];
      }
      red[tid] = ps + ex;
      __syncthreads();
      if (tid < SEQ && (unsigned)(e - c*4096) < 4096u) {
        int j = atomicAdd(&cnt, 1);                  // LDS atomic, block-local
        me[j] = e; mp[j] = ex;
      }
      for (int off = 128; off > 0; off >>= 1) {
        __syncthreads();
        if (tid < off) red[tid] += red[tid + off];
      }
      __syncthreads();
      const float inv = 1.f / red[0];
      const int ncnt = cnt;
      #pragma unroll
      for (int tt = 0; tt < 4; ++tt) {
        const int i4 = c * 1024 + tt * 256 + tid;
        if (i4 < V4) {
          float4 v = reinterpret_cast<const float4*>(out0 + (size_t)b*VOCAB)[i4];
          float4 o;
          o.x = v.x * inv; o.y = v.y * inv; o.z = v.z * inv; o.w = v.w * inv;
          const int base = i4 * 4;
          for (int j = 0; j < ncnt; ++j) {
            unsigned d = (unsigned)(me[j] - base);
            if (d < 4u) (&o.x)[d] += mp[j] * inv;
          }
          reinterpret_cast<float4*>(out0 + (size_t)b*VOCAB)[i4] = o;
        }
      }
    }
  }
}

// ---------------------------------------------------------------------------
extern "C" void kernel_launch(void* const* d_in, const int* in_sizes, int n_in,
                              void* d_out, int out_size, void* d_ws, size_t ws_size,
                              hipStream_t stream) {
  (void)in_sizes; (void)n_in; (void)out_size; (void)ws_size;
  const int*   input_idx  = (const int*)d_in[0];
  const float* encoded    = (const float*)d_in[1];
  const int*   enc_idx    = (const int*)d_in[2];
  const float* prev_state = (const float*)d_in[3];
  const float* weighted   = (const float*)d_in[4];
  const float* embed      = (const float*)d_in[6];
  const float* w_ih       = (const float*)d_in[7];
  const float* w_hh       = (const float*)d_in[8];
  const float* b_ih       = (const float*)d_in[9];
  const float* b_hh       = (const float*)d_in[10];
  const float* wo_w       = (const float*)d_in[11];
  const float* wo_b       = (const float*)d_in[12];
  const float* wc_w       = (const float*)d_in[13];
  const float* wc_b       = (const float*)d_in[14];

  float* out0      = (float*)d_out;                          // 64 x 50000
  float* out_state = out0 + (size_t)BATCH * VOCAB;           // 64 x 512
  float* out_wnew  = out_state + BATCH * HIDDEN;             // 64 x 1024

  // ws (floats): gxp(786432) | ghp(393216) | stateF(16384 = 64KB bf16)
  //              | stateWS(32768) | sccp(64*200*2) | Spart(64*784)  ~= 5.2 MB
  float* ws     = (float*)d_ws;
  float* gxp    = ws;
  float* ghp    = ws + (size_t)8 * BATCH * G3;
  unsigned short* stateF = (unsigned short*)(ws + (size_t)12 * BATCH * G3);
  float* stateWS= ws + (size_t)12 * BATCH * G3 + 16384;
  float* sccp   = stateWS + BATCH * HIDDEN;
  float* Spart  = sccp + (size_t)BATCH * SEQ * NHS;

  void* kargs[] = {
    (void*)&input_idx, (void*)&encoded, (void*)&enc_idx, (void*)&prev_state,
    (void*)&weighted, (void*)&embed, (void*)&w_ih, (void*)&w_hh,
    (void*)&b_ih, (void*)&b_hh, (void*)&wo_w, (void*)&wo_b,
    (void*)&wc_w, (void*)&wc_b,
    (void*)&out0, (void*)&out_state, (void*)&out_wnew,
    (void*)&gxp, (void*)&ghp, (void*)&stateF, (void*)&stateWS,
    (void*)&sccp, (void*)&Spart
  };
  hipLaunchCooperativeKernel((const void*)mega, dim3(GRID), dim3(256),
                             kargs, 0, stream);
}

// Round 14
// 98.422 us; speedup vs baseline: 4.3964x; 4.3964x over previous
//
#include <hip/hip_runtime.h>
#include <hip/hip_bf16.h>
#include <cstdint>
#include <cstddef>

#define VOCAB  50000
#define EMBED  256
#define HIDDEN 512
#define BATCH  64
#define SEQ    200
#define H2     1024
#define XDIM   1280   // EMBED + H2
#define G3     1536   // 3*HIDDEN
#define V4     (VOCAB/4)     // 12500 float4 per row
#define NVB    782           // vocab GEMM blocks (782*64 = 50048 >= 50000)
#define NVBP   784           // Spart row stride
#define NFB    13            // finalize chunks per row (13*4096 >= 50000)
#define NHS    8             // scc H-slices (rider parallelism per row)
#define NSCC   (BATCH*NHS)   // 512 scc rider blocks

typedef __attribute__((ext_vector_type(8))) short short8;
typedef __attribute__((ext_vector_type(4))) float f32x4;

__device__ __forceinline__ short f2bf(float f) {
  uint32_t u = __builtin_bit_cast(uint32_t, f);
  uint32_t r = (u + 0x7fffu + ((u >> 16) & 1u)) >> 16;
  return (short)(r & 0xffffu);
}

__device__ __forceinline__ short8 pack8(float4 v0, float4 v1) {
  short8 fr;
  fr[0]=f2bf(v0.x); fr[1]=f2bf(v0.y); fr[2]=f2bf(v0.z); fr[3]=f2bf(v0.w);
  fr[4]=f2bf(v1.x); fr[5]=f2bf(v1.y); fr[6]=f2bf(v1.z); fr[7]=f2bf(v1.w);
  return fr;
}

// ---------------------------------------------------------------------------
// K1: fused GRU input GEMMs (verified since round 2).
// ---------------------------------------------------------------------------
__launch_bounds__(256)
__global__ void gru_gemm(const int* __restrict__ idx, const float* __restrict__ embed,
                         const float* __restrict__ weighted, const float* __restrict__ h0,
                         const float* __restrict__ w_ih, const float* __restrict__ w_hh,
                         float* __restrict__ gxp, float* __restrict__ ghp) {
  __shared__ __align__(16) short As[4 * 64 * 8];
  const int tid  = threadIdx.x;
  const int wave = tid >> 6, lane = tid & 63;
  const int l15  = lane & 15, lk = lane >> 4;
  const int slice = blockIdx.y;
  const bool isX  = slice < 8;
  const float* B  = isX ? w_ih : w_hh;
  const int ldb   = isX ? XDIM : HIDDEN;
  const int kbeg  = isX ? slice * 160 : (slice - 8) * 128;
  const int kend  = kbeg + (isX ? 160 : 128);
  float* C = isX ? (gxp + (size_t)slice * BATCH * G3)
                 : (ghp + (size_t)(slice - 8) * BATCH * G3);
  const int ncol = blockIdx.x * 64 + wave * 16;

  f32x4 acc0 = {0,0,0,0}, acc1 = {0,0,0,0}, acc2 = {0,0,0,0}, acc3 = {0,0,0,0};

  const int sl  = tid & 63;
  const int sm  = (tid >> 6) * 16 + (sl & 15);
  const int skb = (sl >> 4) * 8;

  const int nrow = ncol + l15;
  const float* Bbase = B + (size_t)nrow * ldb + lk * 8;

  for (int kc = kbeg; kc < kend; kc += 32) {
    {
      const float4* ap;
      if (isX) {
        int col = kc + skb;
        if (col < EMBED) ap = reinterpret_cast<const float4*>(embed + (size_t)idx[sm] * EMBED + col);
        else             ap = reinterpret_cast<const float4*>(weighted + (size_t)sm * H2 + (col - EMBED));
      } else {
        ap = reinterpret_cast<const float4*>(h0 + (size_t)sm * HIDDEN + kc + skb);
      }
      *reinterpret_cast<short8*>(&As[tid * 8]) = pack8(ap[0], ap[1]);
    }
    __syncthreads();
    short8 bf;
    {
      const float4* bp = reinterpret_cast<const float4*>(Bbase + kc);
      bf = pack8(bp[0], bp[1]);
    }
    short8 a0 = *reinterpret_cast<const short8*>(&As[(0*64 + lane)*8]);
    short8 a1 = *reinterpret_cast<const short8*>(&As[(1*64 + lane)*8]);
    short8 a2 = *reinterpret_cast<const short8*>(&As[(2*64 + lane)*8]);
    short8 a3 = *reinterpret_cast<const short8*>(&As[(3*64 + lane)*8]);
    acc0 = __builtin_amdgcn_mfma_f32_16x16x32_bf16(a0, bf, acc0, 0, 0, 0);
    acc1 = __builtin_amdgcn_mfma_f32_16x16x32_bf16(a1, bf, acc1, 0, 0, 0);
    acc2 = __builtin_amdgcn_mfma_f32_16x16x32_bf16(a2, bf, acc2, 0, 0, 0);
    acc3 = __builtin_amdgcn_mfma_f32_16x16x32_bf16(a3, bf, acc3, 0, 0, 0);
    __syncthreads();
  }

  const int n = ncol + l15;
  #pragma unroll
  for (int r = 0; r < 4; ++r) {
    C[(size_t)(0*16 + lk*4 + r) * G3 + n] = acc0[r];
    C[(size_t)(1*16 + lk*4 + r) * G3 + n] = acc1[r];
    C[(size_t)(2*16 + lk*4 + r) * G3 + n] = acc2[r];
    C[(size_t)(3*16 + lk*4 + r) * G3 + n] = acc3[r];
  }
}

// ---------------------------------------------------------------------------
// K2: GRU gates + state to d_out + stateWS + stateF (bf16 fragment-linear).
// ---------------------------------------------------------------------------
__launch_bounds__(256)
__global__ void gru_gates(const float* __restrict__ gxp, const float* __restrict__ ghp,
                          const float* __restrict__ b_ih, const float* __restrict__ b_hh,
                          const float* __restrict__ h0, float* __restrict__ out_state,
                          float* __restrict__ stateWS, unsigned short* __restrict__ stateF) {
  int i = blockIdx.x * 256 + threadIdx.x;
  int b = i >> 9, h = i & 511;
  float xr = b_ih[h], xz = b_ih[HIDDEN + h], xn = b_ih[2*HIDDEN + h];
  #pragma unroll
  for (int s = 0; s < 8; ++s) {
    const float* g = gxp + (size_t)s * BATCH * G3 + (size_t)b * G3;
    xr += g[h]; xz += g[HIDDEN + h]; xn += g[2*HIDDEN + h];
  }
  float hr = b_hh[h], hz = b_hh[HIDDEN + h], hn = b_hh[2*HIDDEN + h];
  #pragma unroll
  for (int s = 0; s < 4; ++s) {
    const float* g = ghp + (size_t)s * BATCH * G3 + (size_t)b * G3;
    hr += g[h]; hz += g[HIDDEN + h]; hn += g[2*HIDDEN + h];
  }
  float r = 1.f / (1.f + __expf(-(xr + hr)));
  float z = 1.f / (1.f + __expf(-(xz + hz)));
  float n = tanhf(xn + r * hn);
  float st = (1.f - z) * n + z * h0[(size_t)b*HIDDEN + h];
  out_state[(size_t)b*HIDDEN + h] = st;
  stateWS[(size_t)b*HIDDEN + h] = st;
  int fi = ((h >> 5) * 4 + (b >> 4)) * 512 + ((b & 15) + 16 * ((h >> 3) & 3)) * 8 + (h & 7);
  stateF[fi] = (unsigned short)f2bf(st);
}

// ---------------------------------------------------------------------------
// K3: vocab GEMM with IN-BLOCK K-SPLIT (the one un-tested axis: concurrency).
// 512-thread blocks, 8 waves: waves 0-3 (kw=0) compute K=[0,256), waves 4-7
// (kw=1) K=[256,512) of the same 64-col tile; partials combined via 16 KB LDS;
// epilogue (bias+exp+store+rowsum) by waves 0-3. Doubles resident waves
// (3.4k -> 6.3k; Occupancy was 16-22%) and halves each wave's dependent
// K-chain (16 -> 8 chunks). Riders (512 blocks) = R9's parallel scc partials.
// NO cross-block atomics. stateF reservation corrected (R11).
// ---------------------------------------------------------------------------
__launch_bounds__(512)
__global__ void vocab_v7(const unsigned short* __restrict__ stateF,
                         const float* __restrict__ stateWS,
                         const float* __restrict__ wo_w, const float* __restrict__ wo_b,
                         const int* __restrict__ eidx, const int* __restrict__ iidx,
                         const float* __restrict__ enc, const float* __restrict__ wc_w,
                         const float* __restrict__ wc_b,
                         float* __restrict__ E, float* __restrict__ sccp,
                         float* __restrict__ Spart) {
  __shared__ float red[512];
  __shared__ int   act[SEQ];
  __shared__ __align__(16) f32x4 LDSX[16][64];    // 16 KB K-split exchange
  const int bid = blockIdx.x;
  const int tid = threadIdx.x;

  if (bid < NSCC) {
    // ------------- scc partial rider: row b, H-slice hs (8 thr per h) ------
    const int b  = bid >> 3, hs = bid & 7;
    const int in0 = iidx[b];
    if (tid < SEQ) {
      int e = eidx[b*SEQ + tid];
      act[tid] = (e != 0 && e == in0);
      sccp[(size_t)(b*SEQ + tid)*NHS + hs] = 0.f;
    }
    __syncthreads();
    const int hl = tid >> 3, kq = tid & 7;        // 64 h x 8 threads
    const int h  = hs*64 + hl;
    const float4* wr = reinterpret_cast<const float4*>(wc_w + (size_t)h*H2) + kq*32;
    const float  sh  = stateWS[(size_t)b*HIDDEN + h];
    const float  bh  = wc_b[h];
    for (int sq = 0; sq < SEQ; ++sq) {
      if (act[sq]) {
        const float4* er = reinterpret_cast<const float4*>(enc + (size_t)b*SEQ*H2 + (size_t)sq*H2) + kq*32;
        float d = 0.f;
        #pragma unroll 8
        for (int k = 0; k < 32; ++k) {
          float4 a = er[k], w = wr[k];
          d += a.x*w.x + a.y*w.y + a.z*w.z + a.w*w.w;
        }
        d += __shfl_xor(d, 1);
        d += __shfl_xor(d, 2);
        d += __shfl_xor(d, 4);
        float ph = (kq == 0) ? tanhf(d + bh) * sh : 0.f;
        red[tid] = ph;
        __syncthreads();
        for (int off = 256; off > 0; off >>= 1) {
          if (tid < off) red[tid] += red[tid + off];
          __syncthreads();
        }
        if (tid == 0) sccp[(size_t)(b*SEQ + sq)*NHS + hs] = red[0];
        __syncthreads();
      }
    }
    return;
  }

  // ---------------- vocab GEMM role (K-split across wave pairs) ------------
  const int vb   = bid - NSCC;
  const int wave = tid >> 6, lane = tid & 63;
  const int w4   = wave & 3, kw = wave >> 2;      // col sub-tile, K-half
  const int l15  = lane & 15, lk = lane >> 4;
  const int ncol = vb * 64 + w4 * 16;
  int nrow = ncol + l15; if (nrow > VOCAB - 1) nrow = VOCAB - 1;
  const float*  Bb = wo_w + (size_t)nrow * HIDDEN + lk * 8;
  const short8* Af = reinterpret_cast<const short8*>(stateF);

  f32x4 acc0 = {0,0,0,0}, acc1 = {0,0,0,0}, acc2 = {0,0,0,0}, acc3 = {0,0,0,0};
  const int c0 = kw * 8;                          // this wave's 8 K-chunks
  #pragma unroll 4
  for (int cc = 0; cc < 8; ++cc) {
    const int c = c0 + cc;
    const float4* bp = reinterpret_cast<const float4*>(Bb + c*32);
    float4 b0 = bp[0], b1 = bp[1];
    short8 a0 = Af[(c*4 + 0)*64 + lane];
    short8 a1 = Af[(c*4 + 1)*64 + lane];
    short8 a2 = Af[(c*4 + 2)*64 + lane];
    short8 a3 = Af[(c*4 + 3)*64 + lane];
    short8 bf = pack8(b0, b1);
    acc0 = __builtin_amdgcn_mfma_f32_16x16x32_bf16(a0, bf, acc0, 0, 0, 0);
    acc1 = __builtin_amdgcn_mfma_f32_16x16x32_bf16(a1, bf, acc1, 0, 0, 0);
    acc2 = __builtin_amdgcn_mfma_f32_16x16x32_bf16(a2, bf, acc2, 0, 0, 0);
    acc3 = __builtin_amdgcn_mfma_f32_16x16x32_bf16(a3, bf, acc3, 0, 0, 0);
  }

  if (kw == 1) {
    LDSX[0*4 + w4][lane] = acc0;
    LDSX[1*4 + w4][lane] = acc1;
    LDSX[2*4 + w4][lane] = acc2;
    LDSX[3*4 + w4][lane] = acc3;
  }
  __syncthreads();
  if (kw == 0) {
    acc0 += LDSX[0*4 + w4][lane];
    acc1 += LDSX[1*4 + w4][lane];
    acc2 += LDSX[2*4 + w4][lane];
    acc3 += LDSX[3*4 + w4][lane];

    const int n = ncol + l15;
    const bool valid = n < VOCAB;
    const float bv = valid ? wo_b[n] : 0.f;
    f32x4 accs[4] = {acc0, acc1, acc2, acc3};
    #pragma unroll
    for (int a = 0; a < 4; ++a) {
      #pragma unroll
      for (int r = 0; r < 4; ++r) {
        float ev = valid ? __expf(accs[a][r] + bv) : 0.f;
        if (valid) E[(size_t)(a*16 + lk*4 + r) * VOCAB + n] = ev;
        float v = ev;
        v += __shfl_xor(v, 1); v += __shfl_xor(v, 2);
        v += __shfl_xor(v, 4); v += __shfl_xor(v, 8);
        if (l15 == 0) red[w4*64 + a*16 + lk*4 + r] = v;   // red as 4x64 rowsums
      }
    }
  }
  __syncthreads();
  if (tid < 64)
    Spart[(size_t)tid * NVBP + vb] =
        red[0*64+tid] + red[1*64+tid] + red[2*64+tid] + red[3*64+tid];
}

// ---------------------------------------------------------------------------
// K4: finalize + scatter + weighted_new. grid = BATCH + 64*NFB. (R9 form.)
// ---------------------------------------------------------------------------
__launch_bounds__(256)
__global__ void finalize_fused(const int* __restrict__ eidx, const int* __restrict__ iidx,
                               const float* __restrict__ sccp, const float* __restrict__ Spart,
                               const float* __restrict__ enc,
                               float* __restrict__ out0, float* __restrict__ wnew) {
  const int bid = blockIdx.x;
  const int tid = threadIdx.x;

  if (bid < BATCH) {
    // ---------------- weighted_new role ----------------
    __shared__ float attn_sh[SEQ];
    __shared__ float fnorm_sh;
    const int b = bid;
    const int in0 = iidx[b];
    if (tid < SEQ) {
      float sc = 0.f;
      #pragma unroll
      for (int hs = 0; hs < NHS; ++hs) sc += sccp[(size_t)(b*SEQ + tid)*NHS + hs];
      int e = eidx[b*SEQ + tid];
      attn_sh[tid] = (e == in0) ? __expf(sc) : 0.f;
    }
    __syncthreads();
    if (tid == 0) {
      float s = 0.f;
      for (int i = 0; i < SEQ; ++i) s += attn_sh[i];
      fnorm_sh = (s > 0.f) ? 1.f / s : 1.f;
    }
    __syncthreads();
    const float f = fnorm_sh;
    float a0 = 0, a1 = 0, a2 = 0, a3 = 0;
    const float4* ep = reinterpret_cast<const float4*>(enc + (size_t)b*SEQ*H2);
    for (int s = 0; s < SEQ; ++s) {
      float a = attn_sh[s];
      if (a != 0.f) {                       // block-uniform, almost always skipped
        a *= f;
        float4 v = ep[(size_t)s*(H2/4) + tid];
        a0 += a*v.x; a1 += a*v.y; a2 += a*v.z; a3 += a*v.w;
      }
    }
    float4 o = {a0, a1, a2, a3};
    reinterpret_cast<float4*>(wnew + (size_t)b*H2)[tid] = o;
    return;
  }

  __shared__ int   me[SEQ];
  __shared__ float mp[SEQ];
  __shared__ float sred[256];
  __shared__ int   cnt;
  const int q = bid - BATCH;
  const int b = q / NFB, c = q % NFB;
  if (tid == 0) cnt = 0;
  float ps = 0.f;
  for (int i = tid; i < NVB; i += 256) ps += Spart[(size_t)b * NVBP + i];
  float ex = 0.f;
  int e = -1;
  if (tid < SEQ) {
    float sc = 0.f;
    #pragma unroll
    for (int hs = 0; hs < NHS; ++hs) sc += sccp[(size_t)(b*SEQ + tid)*NHS + hs];
    ex = __expf(sc);
    e = eidx[b*SEQ + tid];
  }
  sred[tid] = ps + ex;
  __syncthreads();
  if (tid < SEQ && (unsigned)(e - c*4096) < 4096u) {
    int j = atomicAdd(&cnt, 1);             // LDS atomic, block-local
    me[j] = e; mp[j] = ex;
  }
  for (int off = 128; off > 0; off >>= 1) {
    __syncthreads();
    if (tid < off) sred[tid] += sred[tid + off];
  }
  __syncthreads();
  const float inv = 1.f / sred[0];
  const int ncnt = cnt;
  #pragma unroll
  for (int t = 0; t < 4; ++t) {
    const int i4 = c * 1024 + t * 256 + tid;
    if (i4 < V4) {
      float4 v = reinterpret_cast<const float4*>(out0 + (size_t)b*VOCAB)[i4];
      float4 o;
      o.x = v.x * inv; o.y = v.y * inv; o.z = v.z * inv; o.w = v.w * inv;
      const int base = i4 * 4;
      for (int j = 0; j < ncnt; ++j) {
        unsigned d = (unsigned)(me[j] - base);
        if (d < 4u) (&o.x)[d] += mp[j] * inv;
      }
      reinterpret_cast<float4*>(out0 + (size_t)b*VOCAB)[i4] = o;
    }
  }
}

// ---------------------------------------------------------------------------
extern "C" void kernel_launch(void* const* d_in, const int* in_sizes, int n_in,
                              void* d_out, int out_size, void* d_ws, size_t ws_size,
                              hipStream_t stream) {
  (void)in_sizes; (void)n_in; (void)out_size; (void)ws_size;
  const int*   input_idx  = (const int*)d_in[0];
  const float* encoded    = (const float*)d_in[1];
  const int*   enc_idx    = (const int*)d_in[2];
  const float* prev_state = (const float*)d_in[3];
  const float* weighted   = (const float*)d_in[4];
  const float* embed      = (const float*)d_in[6];
  const float* w_ih       = (const float*)d_in[7];
  const float* w_hh       = (const float*)d_in[8];
  const float* b_ih       = (const float*)d_in[9];
  const float* b_hh       = (const float*)d_in[10];
  const float* wo_w       = (const float*)d_in[11];
  const float* wo_b       = (const float*)d_in[12];
  const float* wc_w       = (const float*)d_in[13];
  const float* wc_b       = (const float*)d_in[14];

  float* out0      = (float*)d_out;                          // 64 x 50000
  float* out_state = out0 + (size_t)BATCH * VOCAB;           // 64 x 512
  float* out_wnew  = out_state + BATCH * HIDDEN;             // 64 x 1024

  // ws (floats): gxp(786432) | ghp(393216) | stateF(16384 floats = 64KB bf16,
  // FULL reservation) | stateWS(32768... actually 64*512=32768? no: 32768
  // elements -> 32768 floats? BATCH*HIDDEN = 32768 floats) | sccp(64*200*8)
  // | Spart(64*784)   total ~5.5 MB
  float* ws     = (float*)d_ws;
  float* gxp    = ws;
  float* ghp    = ws + (size_t)8 * BATCH * G3;
  unsigned short* stateF = (unsigned short*)(ws + (size_t)12 * BATCH * G3);
  float* stateWS= ws + (size_t)12 * BATCH * G3 + 16384;      // after 64KB stateF
  float* sccp   = stateWS + BATCH * HIDDEN;
  float* Spart  = sccp + (size_t)BATCH * SEQ * NHS;

  gru_gemm<<<dim3(G3/64, 12), 256, 0, stream>>>(input_idx, embed, weighted, prev_state,
                                                w_ih, w_hh, gxp, ghp);
  gru_gates<<<(BATCH*HIDDEN)/256, 256, 0, stream>>>(gxp, ghp, b_ih, b_hh, prev_state,
                                                    out_state, stateWS, stateF);
  vocab_v7<<<NSCC + NVB, 512, 0, stream>>>(stateF, stateWS, wo_w, wo_b,
                                           enc_idx, input_idx, encoded, wc_w, wc_b,
                                           out0, sccp, Spart);
  finalize_fused<<<BATCH + BATCH*NFB, 256, 0, stream>>>(enc_idx, input_idx, sccp, Spart,
                                                        encoded, out0, out_wnew);
}